// Round 10
// baseline (368.752 us; speedup 1.0000x reference)
//
#include <hip/hip_runtime.h>

#define TT 512
#define LOG2E 1.44269504088896340736f

// ---- DPP helpers (rows of 16 lanes) ----
template <int N>
__device__ __forceinline__ int rorki_(int v) {           // row_ror:N
    return __builtin_amdgcn_update_dpp(v, v, 0x120 + N, 0xf, 0xf, true);
}
template <int N>
__device__ __forceinline__ float rorkf_(float v) { return __int_as_float(rorki_<N>(__float_as_int(v))); }
template <int C>
__device__ __forceinline__ float shrf_(float v) {        // row_shr:N, shifted-in -> 0
    return __int_as_float(__builtin_amdgcn_update_dpp(0, __float_as_int(v), C, 0xf, 0xf, true));
}
__device__ __forceinline__ float sgm_(float v) {         // sigmoid, arg pre-scaled by log2e
    return __builtin_amdgcn_rcpf(1.f + __builtin_amdgcn_exp2f(-v));
}
__device__ __forceinline__ float opq_(float v) {         // opaque copy: breaks CSE so each
    float r = v;                                         // update_dpp stays single-use and
    asm volatile("" : "+v"(r));                          // folds into v_fmac_f32_dpp
    return r;
}

// 7 DPP-FMA taps k=1..7 from copy c
#define CH7(acc, c, W)                          \
    acc = fmaf(rorkf_<1>(c), W[1], acc);        \
    acc = fmaf(rorkf_<2>(c), W[2], acc);        \
    acc = fmaf(rorkf_<3>(c), W[3], acc);        \
    acc = fmaf(rorkf_<4>(c), W[4], acc);        \
    acc = fmaf(rorkf_<5>(c), W[5], acc);        \
    acc = fmaf(rorkf_<6>(c), W[6], acc);        \
    acc = fmaf(rorkf_<7>(c), W[7], acc);
// 7 DPP-FMA taps k=9..15 from copy c
#define CH7H(acc, c, W)                         \
    acc = fmaf(rorkf_<9>(c),  W[9],  acc);      \
    acc = fmaf(rorkf_<10>(c), W[10], acc);      \
    acc = fmaf(rorkf_<11>(c), W[11], acc);      \
    acc = fmaf(rorkf_<12>(c), W[12], acc);      \
    acc = fmaf(rorkf_<13>(c), W[13], acc);      \
    acc = fmaf(rorkf_<14>(c), W[14], acc);      \
    acc = fmaf(rorkf_<15>(c), W[15], acc);

__launch_bounds__(64)
__attribute__((amdgpu_waves_per_eu(2)))
__global__ void gru_gs(const float* __restrict__ x,
                       const float* __restrict__ W1, const float* __restrict__ Ur1,
                       const float* __restrict__ b1,
                       const float* __restrict__ W2, const float* __restrict__ Ur2,
                       const float* __restrict__ b2,
                       const float* __restrict__ Wd, const float* __restrict__ bd,
                       const float* __restrict__ Wo, const float* __restrict__ bo,
                       float* __restrict__ out)
{
    const int lane = threadIdx.x & 63;
    const int j    = lane & 15;          // unit
    const int u1   = j & 7;              // GRU1 unit (pair-duplicated)
    const int hi   = j >> 3;             // z|r side of GRU1 pair
    const int half = (lane >> 4) & 1;    // gate-half: 0 -> {za,ha}, 1 -> {ra,da}
    const int r    = lane >> 5;          // batch row within wave (0/1)
    const int gcol = u1 + 8 * hi;
    const int row  = blockIdx.x * 2 + r;
    const bool ishi = (hi != 0);
    const bool isBf = (half != 0);
    const bool iswr = (j == 15) && (half == 0);

    const float* xbase = x + (size_t)blockIdx.x * 2 * TT * 8;
    const int    xoff  = r * TT * 8 + u1;     // per-lane constant
    float* opl = out + (size_t)row * TT;      // per-lane out pointer, bumped per group

    // ---- trace the ror:k permutation ----
    int Lk[16];
    Lk[0]  = j;
    Lk[1]  = rorki_<1>(j);   Lk[2]  = rorki_<2>(j);   Lk[3]  = rorki_<3>(j);
    Lk[4]  = rorki_<4>(j);   Lk[5]  = rorki_<5>(j);   Lk[6]  = rorki_<6>(j);
    Lk[7]  = rorki_<7>(j);   Lk[8]  = rorki_<8>(j);   Lk[9]  = rorki_<9>(j);
    Lk[10] = rorki_<10>(j);  Lk[11] = rorki_<11>(j);  Lk[12] = rorki_<12>(j);
    Lk[13] = rorki_<13>(j);  Lk[14] = rorki_<14>(j);  Lk[15] = rorki_<15>(j);

    // ---- weight-select per half (same instructions, different data) ----
    float W1sel[16], W2sel[16];                // h2 fan: A1 = za|ra, A2 = ha|da
#pragma unroll
    for (int k = 0; k < 16; ++k) {
        const int s2 = Lk[k];
        W1sel[k] = half ? LOG2E * Ur2[s2 * 48 + 16 + j] : LOG2E * Ur2[s2 * 48 + j];
        W2sel[k] = half ? Wd[s2 * 16 + j]               : Ur2[s2 * 48 + 32 + j];
    }
    float Vsel[8], Vh[8], VC[8], VQ[8], Ax[8], Wx[8];   // h1 fan + x fan
#pragma unroll
    for (int k = 0; k < 8; ++k) {
        const int s1 = Lk[k] & 7;
        Vsel[k] = half ? LOG2E * W2[s1 * 48 + 16 + j] : LOG2E * W2[s1 * 48 + j];
        Vh[k]   = W2[s1 * 48 + 32 + j];
        VC[k]   = LOG2E * Ur1[s1 * 24 + gcol];
        VQ[k]   = Ur1[s1 * 24 + 16 + u1];
        Ax[k]   = LOG2E * W1[s1 * 24 + gcol];
        Wx[k]   = W1[s1 * 24 + 16 + u1];
    }
    const float bias1 = half ? LOG2E * (b2[16 + j] + b2[64 + j])
                             : LOG2E * (b2[j] + b2[48 + j]);
    const float bias2 = half ? bd[j] : b2[80 + j];
    const float bD2   = b2[32 + j];
    const float bAzr  = LOG2E * (b1[gcol] + b1[24 + gcol]);
    const float bGh   = b1[16 + u1];
    const float bIh   = b1[40 + u1];
    const float woj   = Wo[j], boo = bo[0];

    float h1own = 0.f, h2own = 0.f;
    float azrP = bAzr, ihP = bIh;

    const float* xp = xbase;                  // uniform, SGPR-stepped
    float xA = xbase[0 * 8 + xoff];
    float xB = xbase[1 * 8 + xoff];
    float xC = xbase[2 * 8 + xoff];

#define GSTEP(UU, XCUR, XFILL, ST, PF)                                          \
    {                                                                           \
        /* x-fan (recurrence-independent) */                                    \
        const float x0 = XCUR;                                                  \
        float cx1 = opq_(x0), cx2 = opq_(x0);                                   \
        float azr = fmaf(x0, Ax[0], azrP);                                      \
        float ghx = fmaf(x0, Wx[0], bGh);                                       \
        CH7(azr, cx1, Ax)                                                       \
        CH7(ghx, cx2, Wx)                                                       \
        /* h2-fan: A1 = za|ra, A2 = ha|da, two 8-chains each */                 \
        const float h0 = h2own;                                                 \
        float ch1 = opq_(h0), ch2 = opq_(h0), ch3 = opq_(h0), ch4 = opq_(h0);   \
        float A1a = fmaf(h0, W1sel[0], bias1);                                  \
        float A2a = fmaf(h0, W2sel[0], bias2);                                  \
        CH7(A1a, ch1, W1sel)                                                    \
        CH7(A2a, ch3, W2sel)                                                    \
        float A1b = rorkf_<8>(ch2) * W1sel[8];                                  \
        float A2b = rorkf_<8>(ch4) * W2sel[8];                                  \
        CH7H(A1b, ch2, W1sel)                                                   \
        CH7H(A2b, ch4, W2sel)                                                   \
        if (PF) XFILL = xp[xoff + (3 + UU) * 8];   /* SGPR base + imm */        \
        /* GRU1 (duplicated on both halves) */                                  \
        const float s1own = sgm_(azr);                                          \
        const float s1sw  = rorkf_<8>(s1own);                                   \
        const float z1 = ishi ? s1sw : s1own;                                   \
        const float r1 = ishi ? s1own : s1sw;                                   \
        const float hh1 = fmaxf(fmaf(r1, ihP, ghx), 0.f);                       \
        h1own = fmaf(z1, h1own - hh1, hh1);                                     \
        /* h1-fan: A1 taps + hb + next-step GRU1 partials */                    \
        const float n0 = h1own;                                                 \
        float cn1 = opq_(n0), cn2 = opq_(n0), cn3 = opq_(n0), cn4 = opq_(n0);   \
        float nza = n0 * Vsel[0];                                               \
        float hb  = fmaf(n0, Vh[0], bD2);                                       \
        float aN  = fmaf(n0, VC[0], bAzr);                                      \
        float iN  = fmaf(n0, VQ[0], bIh);                                       \
        CH7(nza, cn1, Vsel)                                                     \
        CH7(hb,  cn2, Vh)                                                       \
        CH7(aN,  cn3, VC)                                                       \
        CH7(iN,  cn4, VQ)                                                       \
        azrP = aN; ihP = iN;                                                    \
        /* GRU2: 2 cross-half exchanges (xor-swap-select) */                    \
        const float A1 = (A1a + A1b) + nza;                                     \
        const float s2own = sgm_(A1);                                           \
        const float s2sw  = __shfl_xor(s2own, 16);                              \
        const float z2 = isBf ? s2sw : s2own;                                   \
        const float r2 = isBf ? s2own : s2sw;                                   \
        const float A2   = A2a + A2b;                                           \
        const float A2sw = __shfl_xor(A2, 16);                                  \
        const float hav = isBf ? A2sw : A2;                                     \
        const float dav = isBf ? A2 : A2sw;                                     \
        const float hh2 = fmaxf(fmaf(r2, hav, hb), 0.f);                        \
        h2own = fmaf(z2, h2own - hh2, hh2);                                     \
        /* dense for step s-1 */                                                \
        float e = fmaxf(dav, 0.f) * woj;                                        \
        e += shrf_<0x118>(e);                                                   \
        e += shrf_<0x114>(e);                                                   \
        e += shrf_<0x112>(e);                                                   \
        e += shrf_<0x111>(e);                                                   \
        if (ST) { if (iswr) opl[UU - 1] = e + boo; }                            \
    }

    // ---- prologue: s = 0..3 (no store at s=0) ----
    GSTEP(0, xA, xA, 0, 1)
    GSTEP(1, xB, xB, 1, 1)
    GSTEP(2, xC, xC, 1, 1)
    GSTEP(3, xA, xA, 1, 1)
    { float t = xB; xB = xC; xC = xA; xA = t; }
    xp += 32; opl += 4;

    // ---- main: s0 = 4..504 ----
    for (int s0 = 4; s0 < 508; s0 += 4) {
        GSTEP(0, xA, xA, 1, 1)
        GSTEP(1, xB, xB, 1, 1)
        GSTEP(2, xC, xC, 1, 1)
        GSTEP(3, xA, xA, 1, 1)
        { float t = xB; xB = xC; xC = xA; xA = t; }
        xp += 32; opl += 4;
    }

    // ---- tail: s = 508..511 (prefetch only for s+3 = 511) ----
    GSTEP(0, xA, xA, 1, 1)
    GSTEP(1, xB, xB, 1, 0)
    GSTEP(2, xC, xB, 1, 0)
    GSTEP(3, xA, xB, 1, 0)
#undef GSTEP

    // ---- epilogue: dense for s = 511 from final h2 ----
    {
        const float h0 = h2own;
        float ch3 = opq_(h0), ch4 = opq_(h0);
        float A2a = fmaf(h0, W2sel[0], bias2);
        CH7(A2a, ch3, W2sel)
        float A2b = rorkf_<8>(ch4) * W2sel[8];
        CH7H(A2b, ch4, W2sel)
        const float A2   = A2a + A2b;
        const float A2sw = __shfl_xor(A2, 16);
        const float dav  = isBf ? A2 : A2sw;
        float e = fmaxf(dav, 0.f) * woj;
        e += shrf_<0x118>(e);
        e += shrf_<0x114>(e);
        e += shrf_<0x112>(e);
        e += shrf_<0x111>(e);
        if (iswr) opl[3] = e + boo;
    }
}

extern "C" void kernel_launch(void* const* d_in, const int* in_sizes, int n_in,
                              void* d_out, int out_size, void* d_ws, size_t ws_size,
                              hipStream_t stream) {
    const float* x   = (const float*)d_in[0];
    const float* W1  = (const float*)d_in[1];
    const float* Ur1 = (const float*)d_in[2];
    const float* b1  = (const float*)d_in[3];
    const float* W2  = (const float*)d_in[4];
    const float* Ur2 = (const float*)d_in[5];
    const float* b2  = (const float*)d_in[6];
    const float* Wd  = (const float*)d_in[7];
    const float* bd  = (const float*)d_in[8];
    const float* Wo  = (const float*)d_in[9];
    const float* bo  = (const float*)d_in[10];
    float* out = (float*)d_out;

    dim3 grid(4096 / 2);   // 2048 waves = 2/SIMD with TRUE work split
    dim3 block(64);        // 2 rows x (2 gate-halves x 16 lanes), zero LDS
    gru_gs<<<grid, block, 0, stream>>>(x, W1, Ur1, b1, W2, Ur2, b2,
                                       Wd, bd, Wo, bo, out);
}

// Round 11
// 356.922 us; speedup vs baseline: 1.0331x; 1.0331x over previous
//
#include <hip/hip_runtime.h>

#define TT 512
#define LOG2E 1.44269504088896340736f

// ---- DPP helpers (rows of 16 lanes) ----
template <int N>
__device__ __forceinline__ int rorki_(int v) {           // row_ror:N
    return __builtin_amdgcn_update_dpp(v, v, 0x120 + N, 0xf, 0xf, true);
}
template <int N>
__device__ __forceinline__ float rorkf_(float v) { return __int_as_float(rorki_<N>(__float_as_int(v))); }
template <int C>
__device__ __forceinline__ float shrf_(float v) {        // row_shr:N, shifted-in -> 0
    return __int_as_float(__builtin_amdgcn_update_dpp(0, __float_as_int(v), C, 0xf, 0xf, true));
}
__device__ __forceinline__ float sgm_(float v) {         // sigmoid, arg pre-scaled by log2e
    return __builtin_amdgcn_rcpf(1.f + __builtin_amdgcn_exp2f(-v));
}
__device__ __forceinline__ float opq_(float v) {         // opaque copy: breaks CSE so each
    float r = v;                                         // update_dpp stays single-use and
    asm volatile("" : "+v"(r));                          // folds into v_fmac_f32_dpp
    return r;
}

// 7 DPP-FMA taps k=1..7 from copy c
#define CH7(acc, c, W)                          \
    acc = fmaf(rorkf_<1>(c), W[1], acc);        \
    acc = fmaf(rorkf_<2>(c), W[2], acc);        \
    acc = fmaf(rorkf_<3>(c), W[3], acc);        \
    acc = fmaf(rorkf_<4>(c), W[4], acc);        \
    acc = fmaf(rorkf_<5>(c), W[5], acc);        \
    acc = fmaf(rorkf_<6>(c), W[6], acc);        \
    acc = fmaf(rorkf_<7>(c), W[7], acc);
// 7 DPP-FMA taps k=9..15 from copy c
#define CH7H(acc, c, W)                         \
    acc = fmaf(rorkf_<9>(c),  W[9],  acc);      \
    acc = fmaf(rorkf_<10>(c), W[10], acc);      \
    acc = fmaf(rorkf_<11>(c), W[11], acc);      \
    acc = fmaf(rorkf_<12>(c), W[12], acc);      \
    acc = fmaf(rorkf_<13>(c), W[13], acc);      \
    acc = fmaf(rorkf_<14>(c), W[14], acc);      \
    acc = fmaf(rorkf_<15>(c), W[15], acc);

__launch_bounds__(64)
__attribute__((amdgpu_waves_per_eu(2, 2)))   // PIN: exactly 2 waves/EU -> 256-VGPR budget, no spills
__global__ void gru_gs2(const float* __restrict__ x,
                        const float* __restrict__ W1, const float* __restrict__ Ur1,
                        const float* __restrict__ b1,
                        const float* __restrict__ W2, const float* __restrict__ Ur2,
                        const float* __restrict__ b2,
                        const float* __restrict__ Wd, const float* __restrict__ bd,
                        const float* __restrict__ Wo, const float* __restrict__ bo,
                        float* __restrict__ out)
{
    const int lane = threadIdx.x & 63;
    const int j    = lane & 15;          // unit
    const int u1   = j & 7;              // GRU1 unit (pair-duplicated)
    const int hi   = j >> 3;             // z|r side of GRU1 pair
    const int half = (lane >> 4) & 1;    // gate-half: 0 -> {za,ha}, 1 -> {ra,da}
    const int r    = lane >> 5;          // batch row within wave (0/1)
    const int gcol = u1 + 8 * hi;
    const int row  = blockIdx.x * 2 + r;
    const bool ishi = (hi != 0);
    const bool isBf = (half != 0);
    const bool iswr = (j == 15) && (half == 0);

    const float* xbase = x + (size_t)blockIdx.x * 2 * TT * 8;
    const int    xoff  = r * TT * 8 + u1;     // per-lane constant
    float* opl = out + (size_t)row * TT;      // per-lane out pointer, bumped per group

    // ---- trace the ror:k permutation ----
    int Lk[16];
    Lk[0]  = j;
    Lk[1]  = rorki_<1>(j);   Lk[2]  = rorki_<2>(j);   Lk[3]  = rorki_<3>(j);
    Lk[4]  = rorki_<4>(j);   Lk[5]  = rorki_<5>(j);   Lk[6]  = rorki_<6>(j);
    Lk[7]  = rorki_<7>(j);   Lk[8]  = rorki_<8>(j);   Lk[9]  = rorki_<9>(j);
    Lk[10] = rorki_<10>(j);  Lk[11] = rorki_<11>(j);  Lk[12] = rorki_<12>(j);
    Lk[13] = rorki_<13>(j);  Lk[14] = rorki_<14>(j);  Lk[15] = rorki_<15>(j);

    // ---- weight-select per half (same instructions, different data) ----
    float W1sel[16], W2sel[16];                // h2 fan: A1 = za|ra, A2 = ha|da
#pragma unroll
    for (int k = 0; k < 16; ++k) {
        const int s2 = Lk[k];
        W1sel[k] = half ? LOG2E * Ur2[s2 * 48 + 16 + j] : LOG2E * Ur2[s2 * 48 + j];
        W2sel[k] = half ? Wd[s2 * 16 + j]               : Ur2[s2 * 48 + 32 + j];
    }
    float Vsel[8], Vh[8], VC[8], VQ[8], Ax[8], Wx[8];   // h1 fan + x fan
#pragma unroll
    for (int k = 0; k < 8; ++k) {
        const int s1 = Lk[k] & 7;
        Vsel[k] = half ? LOG2E * W2[s1 * 48 + 16 + j] : LOG2E * W2[s1 * 48 + j];
        Vh[k]   = W2[s1 * 48 + 32 + j];
        VC[k]   = LOG2E * Ur1[s1 * 24 + gcol];
        VQ[k]   = Ur1[s1 * 24 + 16 + u1];
        Ax[k]   = LOG2E * W1[s1 * 24 + gcol];
        Wx[k]   = W1[s1 * 24 + 16 + u1];
    }
    const float bias1 = half ? LOG2E * (b2[16 + j] + b2[64 + j])
                             : LOG2E * (b2[j] + b2[48 + j]);
    const float bias2 = half ? bd[j] : b2[80 + j];
    const float bD2   = b2[32 + j];
    const float bAzr  = LOG2E * (b1[gcol] + b1[24 + gcol]);
    const float bGh   = b1[16 + u1];
    const float bIh   = b1[40 + u1];
    const float woj   = Wo[j], boo = bo[0];

    float h1own = 0.f, h2own = 0.f;
    float azrP = bAzr, ihP = bIh;

    const float* xp = xbase;                  // uniform, SGPR-stepped
    float xA = xbase[0 * 8 + xoff];
    float xB = xbase[1 * 8 + xoff];
    float xC = xbase[2 * 8 + xoff];

#define GSTEP(UU, XCUR, XFILL, ST, PF)                                          \
    {                                                                           \
        /* x-fan (recurrence-independent) */                                    \
        const float x0 = XCUR;                                                  \
        float cx1 = opq_(x0), cx2 = opq_(x0);                                   \
        float azr = fmaf(x0, Ax[0], azrP);                                      \
        float ghx = fmaf(x0, Wx[0], bGh);                                       \
        CH7(azr, cx1, Ax)                                                       \
        CH7(ghx, cx2, Wx)                                                       \
        /* h2-fan: A1 = za|ra, A2 = ha|da, two 8-chains each */                 \
        const float h0 = h2own;                                                 \
        float ch1 = opq_(h0), ch2 = opq_(h0), ch3 = opq_(h0), ch4 = opq_(h0);   \
        float A1a = fmaf(h0, W1sel[0], bias1);                                  \
        float A2a = fmaf(h0, W2sel[0], bias2);                                  \
        CH7(A1a, ch1, W1sel)                                                    \
        CH7(A2a, ch3, W2sel)                                                    \
        float A1b = rorkf_<8>(ch2) * W1sel[8];                                  \
        float A2b = rorkf_<8>(ch4) * W2sel[8];                                  \
        CH7H(A1b, ch2, W1sel)                                                   \
        CH7H(A2b, ch4, W2sel)                                                   \
        if (PF) XFILL = xp[xoff + (3 + UU) * 8];   /* SGPR base + imm */        \
        /* GRU1 (duplicated on both halves) */                                  \
        const float s1own = sgm_(azr);                                          \
        const float s1sw  = rorkf_<8>(s1own);                                   \
        const float z1 = ishi ? s1sw : s1own;                                   \
        const float r1 = ishi ? s1own : s1sw;                                   \
        const float hh1 = fmaxf(fmaf(r1, ihP, ghx), 0.f);                       \
        h1own = fmaf(z1, h1own - hh1, hh1);                                     \
        /* h1-fan: A1 taps + hb + next-step GRU1 partials */                    \
        const float n0 = h1own;                                                 \
        float cn1 = opq_(n0), cn2 = opq_(n0), cn3 = opq_(n0), cn4 = opq_(n0);   \
        float nza = n0 * Vsel[0];                                               \
        float hb  = fmaf(n0, Vh[0], bD2);                                       \
        float aN  = fmaf(n0, VC[0], bAzr);                                      \
        float iN  = fmaf(n0, VQ[0], bIh);                                       \
        CH7(nza, cn1, Vsel)                                                     \
        CH7(hb,  cn2, Vh)                                                       \
        CH7(aN,  cn3, VC)                                                       \
        CH7(iN,  cn4, VQ)                                                       \
        azrP = aN; ihP = iN;                                                    \
        /* GRU2: 2 cross-half exchanges (xor-swap-select) */                    \
        const float A1 = (A1a + A1b) + nza;                                     \
        const float s2own = sgm_(A1);                                           \
        const float s2sw  = __shfl_xor(s2own, 16);                              \
        const float z2 = isBf ? s2sw : s2own;                                   \
        const float r2 = isBf ? s2own : s2sw;                                   \
        const float A2   = A2a + A2b;                                           \
        const float A2sw = __shfl_xor(A2, 16);                                  \
        const float hav = isBf ? A2sw : A2;                                     \
        const float dav = isBf ? A2 : A2sw;                                     \
        const float hh2 = fmaxf(fmaf(r2, hav, hb), 0.f);                        \
        h2own = fmaf(z2, h2own - hh2, hh2);                                     \
        /* dense for step s-1 */                                                \
        float e = fmaxf(dav, 0.f) * woj;                                        \
        e += shrf_<0x118>(e);                                                   \
        e += shrf_<0x114>(e);                                                   \
        e += shrf_<0x112>(e);                                                   \
        e += shrf_<0x111>(e);                                                   \
        if (ST) { if (iswr) opl[UU - 1] = e + boo; }                            \
    }

    // ---- prologue: s = 0..3 (no store at s=0) ----
    GSTEP(0, xA, xA, 0, 1)
    GSTEP(1, xB, xB, 1, 1)
    GSTEP(2, xC, xC, 1, 1)
    GSTEP(3, xA, xA, 1, 1)
    { float t = xB; xB = xC; xC = xA; xA = t; }
    xp += 32; opl += 4;

    // ---- main: s0 = 4..504 ----
    for (int s0 = 4; s0 < 508; s0 += 4) {
        GSTEP(0, xA, xA, 1, 1)
        GSTEP(1, xB, xB, 1, 1)
        GSTEP(2, xC, xC, 1, 1)
        GSTEP(3, xA, xA, 1, 1)
        { float t = xB; xB = xC; xC = xA; xA = t; }
        xp += 32; opl += 4;
    }

    // ---- tail: s = 508..511 (prefetch only for s+3 = 511) ----
    GSTEP(0, xA, xA, 1, 1)
    GSTEP(1, xB, xB, 1, 0)
    GSTEP(2, xC, xB, 1, 0)
    GSTEP(3, xA, xB, 1, 0)
#undef GSTEP

    // ---- epilogue: dense for s = 511 from final h2 ----
    {
        const float h0 = h2own;
        float ch3 = opq_(h0), ch4 = opq_(h0);
        float A2a = fmaf(h0, W2sel[0], bias2);
        CH7(A2a, ch3, W2sel)
        float A2b = rorkf_<8>(ch4) * W2sel[8];
        CH7H(A2b, ch4, W2sel)
        const float A2   = A2a + A2b;
        const float A2sw = __shfl_xor(A2, 16);
        const float dav  = isBf ? A2 : A2sw;
        float e = fmaxf(dav, 0.f) * woj;
        e += shrf_<0x118>(e);
        e += shrf_<0x114>(e);
        e += shrf_<0x112>(e);
        e += shrf_<0x111>(e);
        if (iswr) opl[3] = e + boo;
    }
}

extern "C" void kernel_launch(void* const* d_in, const int* in_sizes, int n_in,
                              void* d_out, int out_size, void* d_ws, size_t ws_size,
                              hipStream_t stream) {
    const float* x   = (const float*)d_in[0];
    const float* W1  = (const float*)d_in[1];
    const float* Ur1 = (const float*)d_in[2];
    const float* b1  = (const float*)d_in[3];
    const float* W2  = (const float*)d_in[4];
    const float* Ur2 = (const float*)d_in[5];
    const float* b2  = (const float*)d_in[6];
    const float* Wd  = (const float*)d_in[7];
    const float* bd  = (const float*)d_in[8];
    const float* Wo  = (const float*)d_in[9];
    const float* bo  = (const float*)d_in[10];
    float* out = (float*)d_out;

    dim3 grid(4096 / 2);   // 2048 waves = 2/SIMD with TRUE work split
    dim3 block(64);        // 2 rows x (2 gate-halves x 16 lanes), zero LDS
    gru_gs2<<<grid, block, 0, stream>>>(x, W1, Ur1, b1, W2, Ur2, b2,
                                        Wd, bd, Wo, bo, out);
}